// Round 5
// baseline (449.302 us; speedup 1.0000x reference)
//
#include <hip/hip_runtime.h>
#include <cfloat>

#define M_UP   32768
#define N_DOWN 8192
#define UPC    128
#define DOWNC  256
#define OUTC   128

#define GB     4.0f               // grid half-extent
#define GC     32                 // cells per axis
#define NCELLS (GC * GC * GC)     // 32768
#define GH     (2.0f * GB / GC)   // 0.25
#define GINVH  (1.0f / GH)

__device__ __forceinline__ void fma4(float4& acc, float s, const float4 w) {
    acc.x = fmaf(s, w.x, acc.x);
    acc.y = fmaf(s, w.y, acc.y);
    acc.z = fmaf(s, w.z, acc.z);
    acc.w = fmaf(s, w.w, acc.w);
}

__device__ __forceinline__ int cell_of(float v) {
    int c = (int)floorf((v + GB) * GINVH);
    return min(max(c, 0), GC - 1);
}

// ---------------------------------------------------------------------------
// K0 prep: transpose weights, build padded point table, zero ALL 32768 cell
// counts. grid covers 32768 + 16384 + 8192 + 32768 = 90112 = 352 blocks.
// ---------------------------------------------------------------------------
__global__ __launch_bounds__(256) void prep(
        const float* __restrict__ W_up, const float* __restrict__ W_down,
        const float* __restrict__ down_points,
        float* __restrict__ wt_up, float* __restrict__ wt_down,
        float4* __restrict__ pts4, int* __restrict__ counts) {
    int e = blockIdx.x * 256 + threadIdx.x;
    if (e < DOWNC * OUTC) {
        int k = e >> 7, c = e & 127;
        wt_down[e] = W_down[c * DOWNC + k];
    } else if (e < DOWNC * OUTC + UPC * OUTC) {
        int e2 = e - DOWNC * OUTC;
        int k = e2 >> 7, c = e2 & 127;
        wt_up[e2] = W_up[c * UPC + k];
    } else if (e < DOWNC * OUTC + UPC * OUTC + N_DOWN) {
        int p = e - (DOWNC * OUTC + UPC * OUTC);
        pts4[p] = make_float4(down_points[3 * p], down_points[3 * p + 1],
                              down_points[3 * p + 2], 0.f);
    } else {
        int c = e - (DOWNC * OUTC + UPC * OUTC + N_DOWN);
        counts[c] = 0;   // c in [0, 32768)
    }
}

// K1: histogram points into cells.
__global__ __launch_bounds__(256) void count_cells(
        const float4* __restrict__ pts4, int* __restrict__ counts) {
    int p = blockIdx.x * 256 + threadIdx.x;
    float4 pt = pts4[p];
    int c = (cell_of(pt.x) * GC + cell_of(pt.y)) * GC + cell_of(pt.z);
    atomicAdd(&counts[c], 1);
}

// K2: exclusive prefix sum over 32768 counts. Single block, 256 threads x
// 128 cells each, two streaming passes (no big register array -> no spill).
__global__ __launch_bounds__(256) void scan_offsets(
        const int* __restrict__ counts, int* __restrict__ offs,
        int* __restrict__ cursor) {
    __shared__ int sd[256];
    const int tid = threadIdx.x;
    const int base = tid * 128;
    int t = 0;
    for (int j = 0; j < 128; ++j) t += counts[base + j];
    sd[tid] = t;
    __syncthreads();
    for (int off = 1; off < 256; off <<= 1) {
        int v = (tid >= off) ? sd[tid - off] : 0;
        __syncthreads();
        sd[tid] += v;
        __syncthreads();
    }
    int run = sd[tid] - t;   // exclusive prefix of this thread's chunk
    for (int j = 0; j < 128; ++j) {
        int c = counts[base + j];
        offs[base + j] = run;
        cursor[base + j] = run;
        run += c;
    }
    if (tid == 255) offs[NCELLS] = run;   // total = 8192
}

// K3: scatter points into cell-sorted order, original index packed in .w.
__global__ __launch_bounds__(256) void scatter_pts(
        const float4* __restrict__ pts4, int* __restrict__ cursor,
        float4* __restrict__ sorted) {
    int p = blockIdx.x * 256 + threadIdx.x;
    float4 pt = pts4[p];
    int c = (cell_of(pt.x) * GC + cell_of(pt.y)) * GC + cell_of(pt.z);
    int pos = atomicAdd(&cursor[c], 1);
    sorted[pos] = make_float4(pt.x, pt.y, pt.z, __int_as_float(p));
}

// ---------------------------------------------------------------------------
// K4: down_f = down_features @ W_down.T + b_down  (8192 x 128)
// ---------------------------------------------------------------------------
__global__ __launch_bounds__(256) void down_proj(
        const float* __restrict__ A, const float* __restrict__ WT,
        const float* __restrict__ bias, float* __restrict__ down_f) {
    const int c4 = threadIdx.x & 31;
    const int rr = threadIdx.x >> 5;
    const int r = blockIdx.x * 8 + rr;
    const float* Ar = A + r * DOWNC;
    float4 acc = {0.f, 0.f, 0.f, 0.f};
    for (int k = 0; k < DOWNC; k += 4) {
        float4 a = *(const float4*)(Ar + k);
        const float4* wp = (const float4*)(WT + k * OUTC) + c4;
        float4 w0 = wp[0], w1 = wp[32], w2 = wp[64], w3 = wp[96];
        fma4(acc, a.x, w0); fma4(acc, a.y, w1);
        fma4(acc, a.z, w2); fma4(acc, a.w, w3);
    }
    float4 b = ((const float4*)bias)[c4];
    acc.x += b.x; acc.y += b.y; acc.z += b.z; acc.w += b.w;
    ((float4*)down_f)[r * 32 + c4] = acc;
}

// ---------------------------------------------------------------------------
// K5: exact 3-NN via uniform grid, expanding Chebyshev shells.
// Shells are disjoint (each cell scanned exactly once); termination uses the
// exact lower bound to the complement of the scanned box (grid-edge faces =
// INF, so clamped out-of-range points/queries remain correct); explicit index
// tie-break makes the result scan-order independent == jax.lax.top_k.
// Distance formula byte-identical to R1-R3 (neighbor-flip-safe).
// ---------------------------------------------------------------------------
__global__ __launch_bounds__(64) void knn_grid(
        const float* __restrict__ up_points,
        const float4* __restrict__ sorted,
        const int* __restrict__ offs,
        float4* __restrict__ wgt, int4* __restrict__ nidx) {
    const int m = blockIdx.x * 64 + threadIdx.x;
    const float qx = up_points[3 * m];
    const float qy = up_points[3 * m + 1];
    const float qz = up_points[3 * m + 2];
    const int ci = cell_of(qx), cj = cell_of(qy), ck = cell_of(qz);

    float d0 = FLT_MAX, d1 = FLT_MAX, d2 = FLT_MAX;
    int i0 = -1, i1 = -1, i2 = -1;

    auto scan = [&](int s, int e) {
        for (int p = s; p < e; ++p) {
            float4 pt = sorted[p];
            float dx = qx - pt.x, dy = qy - pt.y, dz = qz - pt.z;
            float sd = fmaf(dz, dz, fmaf(dy, dy, dx * dx));
            int pi = __float_as_int(pt.w);
            bool b0 = (sd < d0) || (sd == d0 && pi < i0);
            bool b1 = (sd < d1) || (sd == d1 && pi < i1);
            bool b2 = (sd < d2) || (sd == d2 && pi < i2);
            float t2 = b1 ? d1 : (b2 ? sd : d2);
            int  u2 = b1 ? i1 : (b2 ? pi : i2);
            float t1 = b0 ? d0 : (b1 ? sd : d1);
            int  u1 = b0 ? i0 : (b1 ? pi : i1);
            float t0 = b0 ? sd : d0;
            int  u0 = b0 ? pi : i0;
            d0 = t0; d1 = t1; d2 = t2;
            i0 = u0; i1 = u1; i2 = u2;
        }
    };

    for (int r = 0; r <= GC; ++r) {
        if (r > 0) {
            const float INF = FLT_MAX;
            float lxp = (ci + r <= GC - 1) ? ((ci + r) * GH - GB - qx) : INF;
            float lxm = (ci - r >= 0) ? (qx - ((ci - r + 1) * GH - GB)) : INF;
            float lyp = (cj + r <= GC - 1) ? ((cj + r) * GH - GB - qy) : INF;
            float lym = (cj - r >= 0) ? (qy - ((cj - r + 1) * GH - GB)) : INF;
            float lzp = (ck + r <= GC - 1) ? ((ck + r) * GH - GB - qz) : INF;
            float lzm = (ck - r >= 0) ? (qz - ((ck - r + 1) * GH - GB)) : INF;
            float lb = fminf(fminf(fminf(lxp, lxm), fminf(lyp, lym)),
                             fminf(lzp, lzm));
            float lbc = fmaxf(lb, 0.f);
            if (lbc * lbc > d2) break;   // also fires when whole grid scanned
        }
        int xlo = max(ci - r, 0), xhi = min(ci + r, GC - 1);
        int ylo = max(cj - r, 0), yhi = min(cj + r, GC - 1);
        int zlo = max(ck - r, 0), zhi = min(ck + r, GC - 1);
        for (int x = xlo; x <= xhi; ++x) {
            bool xface = (x == ci - r) || (x == ci + r);
            for (int y = ylo; y <= yhi; ++y) {
                bool fullz = xface || (y == cj - r) || (y == cj + r);
                int cbase = (x * GC + y) * GC;
                if (fullz) {
                    scan(offs[cbase + zlo], offs[cbase + zhi + 1]);
                } else {
                    int zm = ck - r, zp = ck + r;
                    if (zm >= 0)      scan(offs[cbase + zm], offs[cbase + zm + 1]);
                    if (zp <= GC - 1) scan(offs[cbase + zp], offs[cbase + zp + 1]);
                }
            }
        }
    }
    float r0 = 1.f / (d0 + 1e-8f);
    float r1 = 1.f / (d1 + 1e-8f);
    float r2 = 1.f / (d2 + 1e-8f);
    float rs = (r0 + r1) + r2;
    wgt[m] = make_float4(r0 / rs, r1 / rs, r2 / rs, 0.f);
    nidx[m] = make_int4(i0, i1, i2, 0);
}

// ---------------------------------------------------------------------------
// K6: fused up-projection + gather + interpolation + bias + add.
// ---------------------------------------------------------------------------
__global__ __launch_bounds__(256) void up_fused(
        const float* __restrict__ A, const float* __restrict__ WT,
        const float* __restrict__ bias, const float* __restrict__ down_f,
        const float4* __restrict__ wgt, const int4* __restrict__ nidx,
        float* __restrict__ out) {
    const int c4 = threadIdx.x & 31;
    const int rr = threadIdx.x >> 5;
    const int q0 = blockIdx.x * 16 + rr;
    const int q1 = q0 + 8;
    const float* A0 = A + q0 * UPC;
    const float* A1 = A + q1 * UPC;
    float4 acc0 = {0.f, 0.f, 0.f, 0.f};
    float4 acc1 = {0.f, 0.f, 0.f, 0.f};
    for (int k = 0; k < UPC; k += 4) {
        float4 a0 = *(const float4*)(A0 + k);
        float4 a1 = *(const float4*)(A1 + k);
        const float4* wp = (const float4*)(WT + k * OUTC) + c4;
        float4 w0 = wp[0], w1 = wp[32], w2 = wp[64], w3 = wp[96];
        fma4(acc0, a0.x, w0); fma4(acc0, a0.y, w1);
        fma4(acc0, a0.z, w2); fma4(acc0, a0.w, w3);
        fma4(acc1, a1.x, w0); fma4(acc1, a1.y, w1);
        fma4(acc1, a1.z, w2); fma4(acc1, a1.w, w3);
    }
    const float4 b = ((const float4*)bias)[c4];
    const float4* df4 = (const float4*)down_f;
    #pragma unroll
    for (int t = 0; t < 2; ++t) {
        const int q = t ? q1 : q0;
        float4 acc = t ? acc1 : acc0;
        float4 wv = wgt[q];
        int4 iv = nidx[q];
        float4 f0 = df4[iv.x * 32 + c4];
        float4 f1 = df4[iv.y * 32 + c4];
        float4 f2 = df4[iv.z * 32 + c4];
        float4 res;
        res.x = acc.x + b.x + fmaf(wv.x, f0.x, fmaf(wv.y, f1.x, wv.z * f2.x));
        res.y = acc.y + b.y + fmaf(wv.x, f0.y, fmaf(wv.y, f1.y, wv.z * f2.y));
        res.z = acc.z + b.z + fmaf(wv.x, f0.z, fmaf(wv.y, f1.z, wv.z * f2.z));
        res.w = acc.w + b.w + fmaf(wv.x, f0.w, fmaf(wv.y, f1.w, wv.z * f2.w));
        ((float4*)out)[q * 32 + c4] = res;
    }
}

extern "C" void kernel_launch(void* const* d_in, const int* in_sizes, int n_in,
                              void* d_out, int out_size, void* d_ws, size_t ws_size,
                              hipStream_t stream) {
    const float* up_points     = (const float*)d_in[0];
    const float* up_features   = (const float*)d_in[1];
    const float* down_points   = (const float*)d_in[2];
    const float* down_features = (const float*)d_in[3];
    const float* W_up          = (const float*)d_in[4];
    const float* b_up          = (const float*)d_in[5];
    const float* W_down        = (const float*)d_in[6];
    const float* b_down        = (const float*)d_in[7];
    float* out = (float*)d_out;

    // ws layout (float units; float4 arrays 16B-aligned)
    float* wt_down = (float*)d_ws;                    // 32768 f
    float* wt_up   = wt_down + 32768;                 // 16384 f
    float4* pts4   = (float4*)(wt_up + 16384);        // 8192 f4
    float4* sorted = pts4 + N_DOWN;                   // 8192 f4
    float4* wgt    = sorted + N_DOWN;                 // 32768 f4
    int4*   nidx   = (int4*)(wgt + M_UP);             // 32768 i4
    float* down_f  = (float*)(nidx + M_UP);           // 1048576 f
    int*   counts  = (int*)(down_f + N_DOWN * OUTC);  // 32768 i
    int*   offs    = counts + NCELLS;                 // 32769 i
    int*   cursor  = offs + NCELLS + 1;               // 32768 i
    // total ~6.2 MB

    prep<<<352, 256, 0, stream>>>(W_up, W_down, down_points,
                                  wt_up, wt_down, pts4, counts);
    count_cells<<<N_DOWN / 256, 256, 0, stream>>>(pts4, counts);
    scan_offsets<<<1, 256, 0, stream>>>(counts, offs, cursor);
    scatter_pts<<<N_DOWN / 256, 256, 0, stream>>>(pts4, cursor, sorted);
    down_proj<<<N_DOWN / 8, 256, 0, stream>>>(down_features, wt_down,
                                              b_down, down_f);
    knn_grid<<<M_UP / 64, 64, 0, stream>>>(up_points, sorted, offs, wgt, nidx);
    up_fused<<<M_UP / 16, 256, 0, stream>>>(up_features, wt_up, b_up,
                                            down_f, wgt, nidx, out);
}